// Round 1
// baseline (4301.971 us; speedup 1.0000x reference)
//
#include <hip/hip_runtime.h>
#include <math.h>

#define Bsz 64
#define Nn  1024
#define Mm  1024
constexpr float EPS_F    = 0.1f;
constexpr float INV_EPS  = 10.0f;
constexpr int   MAX_IT   = 50;
constexpr float THRESH_F = 0.1f;

// workspace layout (floats)
#define U_OFF    0
#define V_OFF    (Bsz*Nn)
#define LMU_OFF  (2*Bsz*Nn)
#define LNU_OFF  (3*Bsz*Nn)
#define ERR_OFF  (4*Bsz*Nn)          // MAX_IT floats, padded to 64
#define BSUM_OFF (4*Bsz*Nn + 64)     // Bsz floats

__device__ inline bool check_done(const float* err, int t) {
    for (int s = 0; s < t; ++s)
        if (err[s] * (1.0f/64.0f) < THRESH_F) return true;
    return false;
}

__global__ void ot_init(const float* __restrict__ pred,
                        const float* __restrict__ target,
                        float* __restrict__ ws) {
    int idx = blockIdx.x * blockDim.x + threadIdx.x;
    if (idx < Bsz*Nn) {
        ws[U_OFF + idx]   = 0.f;
        ws[LMU_OFF + idx] = logf(pred[idx] + 1e-8f);
    }
    int idx2 = idx - Bsz*Nn;
    if (idx2 >= 0 && idx2 < Bsz*Mm) {
        ws[V_OFF + idx2]   = 0.f;
        ws[LNU_OFF + idx2] = logf(target[idx2] + 1e-8f);
    }
    int idx3 = idx - 2*Bsz*Nn;
    if (idx3 >= 0 && idx3 < 128) {
        ws[ERR_OFF + idx3] = 0.f;   // err[50..64) pad + batch_sum[64]
    }
}

// one block per (b,i) row: logsumexp over j, update u, accumulate err
__global__ __launch_bounds__(256) void ot_row(const float* __restrict__ C,
                                              float* __restrict__ ws, int t) {
    __shared__ int   s_done;
    __shared__ float swm[4];
    __shared__ float sws[4];
    __shared__ float s_bcast;
    int tid = threadIdx.x;
    if (tid == 0) s_done = check_done(ws + ERR_OFF, t) ? 1 : 0;
    __syncthreads();
    if (s_done) return;

    int row = blockIdx.x;            // b*N + i
    int b   = row >> 10;
    float u_i = ws[U_OFF + row];
    float4 c4 = ((const float4*)(C + (size_t)row * Mm))[tid];
    float4 v4 = ((const float4*)(ws + V_OFF + (size_t)b * Mm))[tid];
    float x0 = (u_i + v4.x - c4.x) * INV_EPS;
    float x1 = (u_i + v4.y - c4.y) * INV_EPS;
    float x2 = (u_i + v4.z - c4.z) * INV_EPS;
    float x3 = (u_i + v4.w - c4.w) * INV_EPS;

    float m = fmaxf(fmaxf(x0, x1), fmaxf(x2, x3));
    for (int off = 32; off > 0; off >>= 1) m = fmaxf(m, __shfl_down(m, off));
    if ((tid & 63) == 0) swm[tid >> 6] = m;
    __syncthreads();
    if (tid == 0) s_bcast = fmaxf(fmaxf(swm[0], swm[1]), fmaxf(swm[2], swm[3]));
    __syncthreads();
    float gm = s_bcast;

    float s = __expf(x0 - gm) + __expf(x1 - gm) + __expf(x2 - gm) + __expf(x3 - gm);
    for (int off = 32; off > 0; off >>= 1) s += __shfl_down(s, off);
    if ((tid & 63) == 0) sws[tid >> 6] = s;
    __syncthreads();
    if (tid == 0) {
        float gs   = sws[0] + sws[1] + sws[2] + sws[3];
        float lse  = gm + logf(gs);
        float unew = EPS_F * (ws[LMU_OFF + row] - lse) + u_i;
        ws[U_OFF + row] = unew;
        atomicAdd(ws + ERR_OFF + t, fabsf(unew - u_i));
    }
}

// one block per (b, 256-col tile): 1024 threads, 4-way i-split online LSE
__global__ __launch_bounds__(1024) void ot_col(const float* __restrict__ C,
                                               float* __restrict__ ws, int t) {
    __shared__ int   s_done;
    __shared__ float s_u[Nn];
    __shared__ float s_m[4][256];
    __shared__ float s_s[4][256];
    int tid = threadIdx.x;
    if (tid == 0) s_done = check_done(ws + ERR_OFF, t) ? 1 : 0;
    __syncthreads();
    if (s_done) return;

    int blk = blockIdx.x;            // b*4 + jt
    int b   = blk >> 2;
    int jt  = blk & 3;
    int jl  = tid & 255;             // local column
    int q   = tid >> 8;              // i-quarter
    int j   = jt * 256 + jl;

    s_u[tid] = ws[U_OFF + b * Nn + tid];
    __syncthreads();

    float v_j = ws[V_OFF + b * Mm + j];
    const float* col = C + (size_t)b * Nn * Mm + (size_t)q * 256 * Mm + j;

    float m = -INFINITY, s = 0.f;
    #pragma unroll 8
    for (int i = 0; i < 256; ++i) {
        float c  = col[(size_t)i * Mm];
        float x  = (s_u[q * 256 + i] + v_j - c) * INV_EPS;
        float mn = fmaxf(m, x);
        s = s * __expf(m - mn) + __expf(x - mn);
        m = mn;
    }
    s_m[q][jl] = m;
    s_s[q][jl] = s;
    __syncthreads();
    if (q == 0) {
        float m0 = s_m[0][jl], m1 = s_m[1][jl], m2 = s_m[2][jl], m3 = s_m[3][jl];
        float gm = fmaxf(fmaxf(m0, m1), fmaxf(m2, m3));
        float gs = s_s[0][jl] * __expf(m0 - gm) + s_s[1][jl] * __expf(m1 - gm)
                 + s_s[2][jl] * __expf(m2 - gm) + s_s[3][jl] * __expf(m3 - gm);
        float lse  = gm + logf(gs);
        float vnew = EPS_F * (ws[LNU_OFF + b * Mm + j] - lse) + v_j;
        ws[V_OFF + b * Mm + j] = vnew;
    }
}

// pi = exp((-C+u+v)/eps) -> out+1 ; per-batch sum(pi*C) -> ws[BSUM]
__global__ __launch_bounds__(256) void ot_pi(const float* __restrict__ C,
                                             float* __restrict__ ws,
                                             float* __restrict__ out) {
    __shared__ float sws[4];
    int tid = threadIdx.x;
    int row = blockIdx.x;
    int b   = row >> 10;
    float u_i = ws[U_OFF + row];
    float4 c4 = ((const float4*)(C + (size_t)row * Mm))[tid];
    float4 v4 = ((const float4*)(ws + V_OFF + (size_t)b * Mm))[tid];
    float p0 = __expf((u_i + v4.x - c4.x) * INV_EPS);
    float p1 = __expf((u_i + v4.y - c4.y) * INV_EPS);
    float p2 = __expf((u_i + v4.z - c4.z) * INV_EPS);
    float p3 = __expf((u_i + v4.w - c4.w) * INV_EPS);
    float4 p = {p0, p1, p2, p3};
    ((float4*)(out + 1 + (size_t)row * Mm))[tid] = p;

    float part = p0 * c4.x + p1 * c4.y + p2 * c4.z + p3 * c4.w;
    for (int off = 32; off > 0; off >>= 1) part += __shfl_down(part, off);
    if ((tid & 63) == 0) sws[tid >> 6] = part;
    __syncthreads();
    if (tid == 0) atomicAdd(ws + BSUM_OFF + b, sws[0] + sws[1] + sws[2] + sws[3]);
}

__global__ void ot_fin(const float* __restrict__ ws, float* __restrict__ out) {
    float x = (threadIdx.x < Bsz) ? ws[BSUM_OFF + threadIdx.x] : 0.f;
    for (int off = 32; off > 0; off >>= 1) x += __shfl_down(x, off);
    if (threadIdx.x == 0) out[0] = x * (1.0f / 64.0f);
}

extern "C" void kernel_launch(void* const* d_in, const int* in_sizes, int n_in,
                              void* d_out, int out_size, void* d_ws, size_t ws_size,
                              hipStream_t stream) {
    const float* pred   = (const float*)d_in[0];
    const float* target = (const float*)d_in[1];
    const float* C      = (const float*)d_in[2];
    float* ws  = (float*)d_ws;
    float* out = (float*)d_out;

    int init_items = 2 * Bsz * Nn + 128;
    ot_init<<<(init_items + 255) / 256, 256, 0, stream>>>(pred, target, ws);
    for (int t = 0; t < MAX_IT; ++t) {
        ot_row<<<Bsz * Nn, 256, 0, stream>>>(C, ws, t);
        ot_col<<<Bsz * 4, 1024, 0, stream>>>(C, ws, t);
    }
    ot_pi<<<Bsz * Nn, 256, 0, stream>>>(C, ws, out);
    ot_fin<<<1, 64, 0, stream>>>(ws, out);
}